// Round 2
// baseline (225.178 us; speedup 1.0000x reference)
//
#include <hip/hip_runtime.h>
#include <stdint.h>

#define KSTEPS 24              // 768 / 32
#define TOKENS 16384           // B*S

typedef short short8 __attribute__((ext_vector_type(8)));
typedef float fx4 __attribute__((ext_vector_type(4)));
typedef unsigned short u16;
typedef u16 u16x4 __attribute__((ext_vector_type(4)));

static __device__ __forceinline__ u16 f2bf(float f) {
  union { float f; unsigned u; } v; v.f = f;
  return (u16)((v.u + 0x7fffu + ((v.u >> 16) & 1u)) >> 16);
}

static __device__ __forceinline__ fx4 mfma16(short8 a, short8 b, fx4 c) {
  return __builtin_amdgcn_mfma_f32_16x16x32_bf16(a, b, c, 0, 0, 0);
}

// async global->LDS, 16B/lane; lds dest = wave-uniform base + lane*16
static __device__ __forceinline__ void async16(const void* g, void* l) {
  __builtin_amdgcn_global_load_lds(
      (const __attribute__((address_space(1))) void*)g,
      (__attribute__((address_space(3))) void*)(unsigned int)(uintptr_t)l,
      16, 0, 0);
}

// ---------------- prep: W[768][64] fp32 (q,k,v) -> bf16 pre-fragmented B-operand layout
__global__ void prep_w_kernel(const float* __restrict__ Wq, const float* __restrict__ Wk,
                              const float* __restrict__ Wv, u16* __restrict__ wfrag) {
  int idx  = blockIdx.x * 256 + threadIdx.x;   // 72*256 = 18432 = 3*24*4*64
  int lane = idx & 63;
  int fid  = idx >> 6;
  int nt   = fid & 3;
  int ks   = (fid >> 2) % KSTEPS;
  int mat  = fid / (KSTEPS * 4);
  const float* W = (mat == 0) ? Wq : (mat == 1) ? Wk : Wv;
  int n  = nt * 16 + (lane & 15);
  int k0 = ks * 32 + (lane >> 4) * 8;
  short8 out;
#pragma unroll
  for (int j = 0; j < 8; j++) out[j] = (short)f2bf(W[(size_t)(k0 + j) * 64 + n]);
  *(short8*)(wfrag + (size_t)idx * 8) = out;
}

// ---------------- projection: 32 tokens/block, 128 threads (2 waves), LDS-staged x
__global__ __launch_bounds__(128) void proj_kernel(const float* __restrict__ x,
                                                   const u16* __restrict__ wfrag,
                                                   u16* __restrict__ qb,
                                                   u16* __restrict__ kb,
                                                   u16* __restrict__ vT) {
  __shared__ float xs[2][32 * 64];  // [dbuf][tok][64 floats], chunk-swizzled, 8KB each
  int w = threadIdx.x >> 6, lane = threadIdx.x & 63;
  int ln = lane & 15, quad = lane >> 4;
  int s0 = blockIdx.x * 32;

  fx4 acc[3][4];
#pragma unroll
  for (int m = 0; m < 3; m++)
#pragma unroll
    for (int nt = 0; nt < 4; nt++) acc[m][nt] = (fx4){0.f, 0.f, 0.f, 0.f};

  int l4 = lane >> 4, slot16 = lane & 15;   // staging: 16 lanes cover one 256B row
  // prologue stage of ks2=0 into buf0: 8 calls (2 ksteps worth = 32 tok x 64 floats)
#pragma unroll
  for (int j = 0; j < 4; j++) {
    int c = w * 4 + j;
    int row = c * 4 + l4;
    int chunk = (slot16 & 8) | ((slot16 ^ row) & 7);
    async16(x + (size_t)(s0 + row) * 768 + 0 * 64 + chunk * 4, (char*)xs[0] + c * 1024);
  }

  int r = w * 16 + ln;   // token row this lane's A-frag uses
  for (int ks2 = 0; ks2 < 12; ks2++) {
    __syncthreads();                        // publishes buf ks2&1
    if (ks2 < 11) {
      int buf = (ks2 + 1) & 1;
#pragma unroll
      for (int j = 0; j < 4; j++) {
        int c = w * 4 + j;
        int row = c * 4 + l4;
        int chunk = (slot16 & 8) | ((slot16 ^ row) & 7);
        async16(x + (size_t)(s0 + row) * 768 + (ks2 + 1) * 64 + chunk * 4,
                (char*)xs[buf] + c * 1024);
      }
    }
    const float* xb_ = xs[ks2 & 1];
#pragma unroll
    for (int kk = 0; kk < 2; kk++) {
      int c0 = kk * 8 + 2 * quad;
      int sl0 = (c0 & 8) | ((c0 ^ r) & 7);
      int sl1 = (c0 & 8) | (((c0 + 1) ^ r) & 7);
      fx4 xa = *(const fx4*)(xb_ + r * 64 + sl0 * 4);
      fx4 xv = *(const fx4*)(xb_ + r * 64 + sl1 * 4);
      short8 af;
#pragma unroll
      for (int j = 0; j < 4; j++) { af[j] = (short)f2bf(xa[j]); af[4 + j] = (short)f2bf(xv[j]); }
      int ks = ks2 * 2 + kk;
      const u16* wp = wfrag + ((size_t)ks * 256 + lane) * 8;
#pragma unroll
      for (int m = 0; m < 3; m++)
#pragma unroll
        for (int nt = 0; nt < 4; nt++) {
          short8 bf = *(const short8*)(wp + ((size_t)m * KSTEPS * 256 + nt * 64) * 8);
          acc[m][nt] = mfma16(af, bf, acc[m][nt]);
        }
    }
  }

  // epilogue: C/D layout col = lane&15, row = quad*4 + reg
#pragma unroll
  for (int nt = 0; nt < 4; nt++) {
    int d = nt * 16 + ln;
    int tok0 = s0 + w * 16 + quad * 4;
#pragma unroll
    for (int reg = 0; reg < 4; reg++) {
      int tok = tok0 + reg;
      qb[(size_t)tok * 64 + d] = f2bf(acc[0][nt][reg] * 0.125f);
      kb[(size_t)tok * 64 + d] = f2bf(acc[1][nt][reg]);
    }
    int b = tok0 >> 12, s = tok0 & 4095;
    u16x4 vp;
#pragma unroll
    for (int reg = 0; reg < 4; reg++) vp[reg] = f2bf(acc[2][nt][reg]);
    *(u16x4*)(vT + ((size_t)b * 64 + d) * 4096 + s) = vp;
  }
}

// stage one 64-key K tile + VT tile (16KB), chunk-swizzled source, this wave does half
static __device__ __forceinline__ void stage_kv(const u16* kbb, const u16* vtb,
                                                u16* kdst, u16* vdst,
                                                int t, int rw, int lane) {
  int l3 = lane >> 3, slot = lane & 7;
#pragma unroll
  for (int c = 0; c < 4; c++) {
    int row = rw * 32 + c * 8 + l3;
    int ch = slot ^ (row & 7);
    async16(kbb + ((size_t)t * 64 + row) * 64 + ch * 8, (char*)kdst + rw * 4096 + c * 1024);
    async16(vtb + (size_t)row * 4096 + t * 64 + ch * 8, (char*)vdst + rw * 4096 + c * 1024);
  }
}

// ---------------- flash attention: BM=32, 4 waves = 2 row-waves x 2 kt-groups
__global__ __launch_bounds__(256) void attn_kernel(const u16* __restrict__ qb,
                                                   const u16* __restrict__ kb,
                                                   const u16* __restrict__ vT,
                                                   float* __restrict__ out) {
  __shared__ u16 stg[2][2][2][64 * 64];   // [group][dbuf][K|VT][tile] = 64KB
  __shared__ u16 Ps[4][16 * 72];          // per-wave P round-trip, padded rows

  int b = blockIdx.y;
  int qt = 127 - blockIdx.x;              // big blocks first
  int w = threadIdx.x >> 6, lane = threadIdx.x & 63;
  int g = w >> 1, rw = w & 1;
  int ln = lane & 15, quad = lane >> 4;
  int q0 = qt * 32;

  const u16* qbb = qb + (size_t)b * 4096 * 64;
  const u16* kbb = kb + (size_t)b * 4096 * 64;
  const u16* vtb = vT + (size_t)b * 64 * 4096;
  float* outb = out + (size_t)b * 4096 * 64;

  short8 qf0 = *(const short8*)(qbb + (size_t)(q0 + rw * 16 + ln) * 64 + quad * 8);
  short8 qf1 = *(const short8*)(qbb + (size_t)(q0 + rw * 16 + ln) * 64 + 32 + quad * 8);

  fx4 o[4];
#pragma unroll
  for (int nt2 = 0; nt2 < 4; nt2++) o[nt2] = (fx4){0.f, 0.f, 0.f, 0.f};
  float m_i[4] = {-1e30f, -1e30f, -1e30f, -1e30f};
  float l_i[4] = {0.f, 0.f, 0.f, 0.f};

  int n = (qt + 2) >> 1;     // 64-key tiles this q-block needs
  int R = (n + 1) >> 1;      // rounds per kt-group

  if (g < n) stage_kv(kbb, vtb, stg[g][0][0], stg[g][0][1], g, rw, lane);

  for (int rr = 0; rr < R; rr++) {
    __syncthreads();                       // publishes buf rr&1 (drains vmcnt)
    int tn = 2 * (rr + 1) + g;
    if (tn < n)
      stage_kv(kbb, vtb, stg[g][(rr + 1) & 1][0], stg[g][(rr + 1) & 1][1], tn, rw, lane);
    int t = 2 * rr + g;
    if (t < n) {
      const u16* Kb = stg[g][rr & 1][0];
      const u16* Vb = stg[g][rr & 1][1];
      fx4 sA[4];
#pragma unroll
      for (int nt = 0; nt < 4; nt++) {
        int row = nt * 16 + ln;
        int s0_ = quad ^ (row & 7), s1_ = (quad + 4) ^ (row & 7);
        short8 kf0 = *(const short8*)(Kb + row * 64 + s0_ * 8);
        short8 kf1 = *(const short8*)(Kb + row * 64 + s1_ * 8);
        sA[nt] = mfma16(qf0, kf0, (fx4){0.f, 0.f, 0.f, 0.f});
        sA[nt] = mfma16(qf1, kf1, sA[nt]);
      }
      if (t == n - 1) {  // only the diagonal-overlapping tile needs masking
#pragma unroll
        for (int nt = 0; nt < 4; nt++)
#pragma unroll
          for (int reg = 0; reg < 4; reg++) {
            int col = t * 64 + nt * 16 + ln;
            int rowg = q0 + rw * 16 + quad * 4 + reg;
            if (col > rowg) sA[nt][reg] = -1e30f;
          }
      }
      float alpha[4];
#pragma unroll
      for (int reg = 0; reg < 4; reg++) {
        float v = fmaxf(fmaxf(sA[0][reg], sA[1][reg]), fmaxf(sA[2][reg], sA[3][reg]));
#pragma unroll
        for (int off = 1; off < 16; off <<= 1) v = fmaxf(v, __shfl_xor(v, off));
        float mn = fmaxf(m_i[reg], v);
        alpha[reg] = __expf(m_i[reg] - mn);
        m_i[reg] = mn;
      }
      float p[4][4];
#pragma unroll
      for (int nt = 0; nt < 4; nt++)
#pragma unroll
        for (int reg = 0; reg < 4; reg++) p[nt][reg] = __expf(sA[nt][reg] - m_i[reg]);
#pragma unroll
      for (int reg = 0; reg < 4; reg++) {
        float sgm = p[0][reg] + p[1][reg] + p[2][reg] + p[3][reg];
#pragma unroll
        for (int off = 1; off < 16; off <<= 1) sgm += __shfl_xor(sgm, off);
        l_i[reg] = l_i[reg] * alpha[reg] + sgm;
      }
#pragma unroll
      for (int nt2 = 0; nt2 < 4; nt2++)
#pragma unroll
        for (int reg = 0; reg < 4; reg++) o[nt2][reg] *= alpha[reg];

#pragma unroll
      for (int nt = 0; nt < 4; nt++)
#pragma unroll
        for (int reg = 0; reg < 4; reg++)
          Ps[w][(quad * 4 + reg) * 72 + nt * 16 + ln] = f2bf(p[nt][reg]);

      short8 pf0 = *(const short8*)(&Ps[w][ln * 72 + quad * 8]);
      short8 pf1 = *(const short8*)(&Ps[w][ln * 72 + 32 + quad * 8]);
#pragma unroll
      for (int nt2 = 0; nt2 < 4; nt2++) {
        int row = nt2 * 16 + ln;
        int s0_ = quad ^ (row & 7), s1_ = (quad + 4) ^ (row & 7);
        short8 vf0 = *(const short8*)(Vb + row * 64 + s0_ * 8);
        short8 vf1 = *(const short8*)(Vb + row * 64 + s1_ * 8);
        o[nt2] = mfma16(pf0, vf0, o[nt2]);
        o[nt2] = mfma16(pf1, vf1, o[nt2]);
      }
    }
  }

  // merge the two kt-groups' partial (m,l,o) per Q-row, then normalize + store
  __syncthreads();
  float* cmb = (float*)&stg[0][0][0][0];   // o: [rw][16][68]; m at 2176, l at 2208
  if (g == 1) {
#pragma unroll
    for (int nt2 = 0; nt2 < 4; nt2++)
#pragma unroll
      for (int reg = 0; reg < 4; reg++)
        cmb[rw * 1088 + (quad * 4 + reg) * 68 + nt2 * 16 + ln] = o[nt2][reg];
    if (ln == 0) {
#pragma unroll
      for (int reg = 0; reg < 4; reg++) {
        cmb[2176 + rw * 16 + quad * 4 + reg] = m_i[reg];
        cmb[2208 + rw * 16 + quad * 4 + reg] = l_i[reg];
      }
    }
  }
  __syncthreads();
  if (g == 0) {
    float a0[4], a1[4], inv[4];
#pragma unroll
    for (int reg = 0; reg < 4; reg++) {
      float m1 = cmb[2176 + rw * 16 + quad * 4 + reg];
      float l1 = cmb[2208 + rw * 16 + quad * 4 + reg];
      float mf = fmaxf(m_i[reg], m1);
      a0[reg] = __expf(m_i[reg] - mf);
      a1[reg] = __expf(m1 - mf);
      inv[reg] = 1.0f / (l_i[reg] * a0[reg] + l1 * a1[reg]);
    }
#pragma unroll
    for (int nt2 = 0; nt2 < 4; nt2++)
#pragma unroll
      for (int reg = 0; reg < 4; reg++) {
        float o1 = cmb[rw * 1088 + (quad * 4 + reg) * 68 + nt2 * 16 + ln];
        int rowg = q0 + rw * 16 + quad * 4 + reg;
        outb[(size_t)rowg * 64 + nt2 * 16 + ln] =
            (o[nt2][reg] * a0[reg] + o1 * a1[reg]) * inv[reg];
      }
  }
}

extern "C" void kernel_launch(void* const* d_in, const int* in_sizes, int n_in,
                              void* d_out, int out_size, void* d_ws, size_t ws_size,
                              hipStream_t stream) {
  const float* x  = (const float*)d_in[0];
  const float* Wq = (const float*)d_in[1];
  const float* Wk = (const float*)d_in[2];
  const float* Wv = (const float*)d_in[3];

  u16* qbw = (u16*)d_ws;                          // [16384][64] bf16
  u16* kbw = qbw + (size_t)TOKENS * 64;           // [16384][64] bf16
  u16* vtw = kbw + (size_t)TOKENS * 64;           // [4][64][4096] bf16
  u16* wfr = vtw + (size_t)TOKENS * 64;           // [3][24][4][64][8] bf16

  prep_w_kernel<<<72, 256, 0, stream>>>(Wq, Wk, Wv, wfr);
  proj_kernel<<<TOKENS / 32, 128, 0, stream>>>(x, wfr, qbw, kbw, vtw);
  attn_kernel<<<dim3(128, 4), 256, 0, stream>>>(qbw, kbw, vtw, (float*)d_out);
}

// Round 3
// 170.884 us; speedup vs baseline: 1.3177x; 1.3177x over previous
//
#include <hip/hip_runtime.h>
#include <stdint.h>

#define KSTEPS 24              // 768 / 32
#define TOKENS 16384           // B*S

typedef short short8 __attribute__((ext_vector_type(8)));
typedef float fx4 __attribute__((ext_vector_type(4)));
typedef unsigned short u16;
typedef u16 u16x4 __attribute__((ext_vector_type(4)));

static __device__ __forceinline__ u16 f2bf(float f) {
  union { float f; unsigned u; } v; v.f = f;
  return (u16)((v.u + 0x7fffu + ((v.u >> 16) & 1u)) >> 16);
}

static __device__ __forceinline__ fx4 mfma16(short8 a, short8 b, fx4 c) {
  return __builtin_amdgcn_mfma_f32_16x16x32_bf16(a, b, c, 0, 0, 0);
}

// async global->LDS, 16B/lane; lds dest = wave-uniform base + lane*16
static __device__ __forceinline__ void async16(const void* g, void* l) {
  __builtin_amdgcn_global_load_lds(
      (const __attribute__((address_space(1))) void*)g,
      (__attribute__((address_space(3))) void*)(unsigned int)(uintptr_t)l,
      16, 0, 0);
}

// ---------------- prep: W[768][64] fp32 (q,k,v) -> bf16 pre-fragmented B-operand layout
// wfrag[mat][ks][nt][lane][8]; elem j = W[ks*32 + (lane>>4)*8 + j][nt*16 + (lane&15)]
__global__ void prep_w_kernel(const float* __restrict__ Wq, const float* __restrict__ Wk,
                              const float* __restrict__ Wv, u16* __restrict__ wfrag) {
  int idx  = blockIdx.x * 256 + threadIdx.x;   // 72*256 = 18432 = 3*24*4*64
  int lane = idx & 63;
  int fid  = idx >> 6;
  int nt   = fid & 3;
  int ks   = (fid >> 2) % KSTEPS;
  int mat  = fid / (KSTEPS * 4);
  const float* W = (mat == 0) ? Wq : (mat == 1) ? Wk : Wv;
  int n  = nt * 16 + (lane & 15);
  int k0 = ks * 32 + (lane >> 4) * 8;
  short8 out;
#pragma unroll
  for (int j = 0; j < 8; j++) out[j] = (short)f2bf(W[(size_t)(k0 + j) * 64 + n]);
  *(short8*)(wfrag + (size_t)idx * 8) = out;
}

// ---------------- projection GEMM: 32 tok/block, 256 thr, W+x staged in LDS, dbuf
// waves: rw = w>>1 picks token-half (16 tok), cs = w&1 picks 6 of 12 (mat,nt) col-tiles
__global__ __launch_bounds__(256) void proj_kernel(const float* __restrict__ x,
                                                   const u16* __restrict__ wfrag,
                                                   u16* __restrict__ qb,
                                                   u16* __restrict__ kb,
                                                   u16* __restrict__ vT) {
  __shared__ float xs[2][32 * 32];    // [dbuf][tok][32 floats] chunk-swizzled, 4KB each
  __shared__ u16  Ws[2][12 * 512];    // [dbuf][f=(m*4+nt)][lane][8], 12KB each

  int w = threadIdx.x >> 6, lane = threadIdx.x & 63;
  int ln = lane & 15, quad = lane >> 4;
  int rw = w >> 1, cs = w & 1;
  int s0 = blockIdx.x * 32;

  fx4 acc[6];
#pragma unroll
  for (int j = 0; j < 6; j++) acc[j] = (fx4){0.f, 0.f, 0.f, 0.f};

  // staging geometry (per thread, constant across ksteps)
  int srow  = w * 8 + (lane >> 3);           // token row this thread stages
  int slot  = lane & 7;                       // dst 16B slot within the row
  int chunk = slot ^ (srow & 7);              // swizzled source chunk
  const float* xsrc = x + (size_t)(s0 + srow) * 768 + chunk * 4;

  // prologue: stage kstep 0 into buf 0
#pragma unroll
  for (int m = 0; m < 3; m++)
    async16(wfrag + ((size_t)(m * KSTEPS + 0) * 256 + w * 64 + lane) * 8,
            (char*)Ws[0] + m * 4096 + w * 1024 + lane * 16);
  async16(xsrc, (char*)xs[0] + w * 1024 + lane * 16);

  int r = rw * 16 + ln;                       // A-frag token row for this lane
  for (int ks = 0; ks < KSTEPS; ks++) {
    __syncthreads();                          // publishes buf ks&1
    if (ks < KSTEPS - 1) {
      int buf = (ks + 1) & 1;
#pragma unroll
      for (int m = 0; m < 3; m++)
        async16(wfrag + ((size_t)(m * KSTEPS + ks + 1) * 256 + w * 64 + lane) * 8,
                (char*)Ws[buf] + m * 4096 + w * 1024 + lane * 16);
      async16(xsrc + (ks + 1) * 32, (char*)xs[buf] + w * 1024 + lane * 16);
    }
    const float* xb = xs[ks & 1];
    const u16*  wb = Ws[ks & 1];
    int sl0 = (2 * quad)     ^ (r & 7);
    int sl1 = (2 * quad + 1) ^ (r & 7);
    fx4 xa = *(const fx4*)(xb + r * 32 + sl0 * 4);
    fx4 xv = *(const fx4*)(xb + r * 32 + sl1 * 4);
    short8 af;
#pragma unroll
    for (int j = 0; j < 4; j++) { af[j] = (short)f2bf(xa[j]); af[4 + j] = (short)f2bf(xv[j]); }
#pragma unroll
    for (int j = 0; j < 6; j++) {
      short8 bf = *(const short8*)(wb + (cs * 6 + j) * 512 + lane * 8);
      acc[j] = mfma16(af, bf, acc[j]);
    }
  }

  // epilogue: C/D layout col = lane&15, row = quad*4 + reg
  int tok0 = s0 + rw * 16 + quad * 4;
#pragma unroll
  for (int j = 0; j < 6; j++) {
    int f = cs * 6 + j;                       // 0..11 = (mat*4 + nt)
    int d = (f & 3) * 16 + ln;
    if (f < 4) {
#pragma unroll
      for (int reg = 0; reg < 4; reg++)
        qb[(size_t)(tok0 + reg) * 64 + d] = f2bf(acc[j][reg] * 0.125f);
    } else if (f < 8) {
#pragma unroll
      for (int reg = 0; reg < 4; reg++)
        kb[(size_t)(tok0 + reg) * 64 + d] = f2bf(acc[j][reg]);
    } else {
      int b = tok0 >> 12, s = tok0 & 4095;
      u16x4 vp;
#pragma unroll
      for (int reg = 0; reg < 4; reg++) vp[reg] = f2bf(acc[j][reg]);
      *(u16x4*)(vT + ((size_t)b * 64 + d) * 4096 + s) = vp;
    }
  }
}

// stage one 64-key K tile + VT tile (16KB), chunk-swizzled source, this wave does half
static __device__ __forceinline__ void stage_kv(const u16* kbb, const u16* vtb,
                                                u16* kdst, u16* vdst,
                                                int t, int rw, int lane) {
  int l3 = lane >> 3, slot = lane & 7;
#pragma unroll
  for (int c = 0; c < 4; c++) {
    int row = rw * 32 + c * 8 + l3;
    int ch = slot ^ (row & 7);
    async16(kbb + ((size_t)t * 64 + row) * 64 + ch * 8, (char*)kdst + rw * 4096 + c * 1024);
    async16(vtb + (size_t)row * 4096 + t * 64 + ch * 8, (char*)vdst + rw * 4096 + c * 1024);
  }
}

// ---------------- flash attention: BM=32, 4 waves = 2 row-waves x 2 kt-groups
__global__ __launch_bounds__(256) void attn_kernel(const u16* __restrict__ qb,
                                                   const u16* __restrict__ kb,
                                                   const u16* __restrict__ vT,
                                                   float* __restrict__ out) {
  __shared__ u16 stg[2][2][2][64 * 64];   // [group][dbuf][K|VT][tile] = 64KB
  __shared__ u16 Ps[4][16 * 72];          // per-wave P round-trip, padded rows

  int b = blockIdx.y;
  int qt = 127 - blockIdx.x;              // big blocks first
  int w = threadIdx.x >> 6, lane = threadIdx.x & 63;
  int g = w >> 1, rw = w & 1;
  int ln = lane & 15, quad = lane >> 4;
  int q0 = qt * 32;

  const u16* qbb = qb + (size_t)b * 4096 * 64;
  const u16* kbb = kb + (size_t)b * 4096 * 64;
  const u16* vtb = vT + (size_t)b * 64 * 4096;
  float* outb = out + (size_t)b * 4096 * 64;

  short8 qf0 = *(const short8*)(qbb + (size_t)(q0 + rw * 16 + ln) * 64 + quad * 8);
  short8 qf1 = *(const short8*)(qbb + (size_t)(q0 + rw * 16 + ln) * 64 + 32 + quad * 8);

  fx4 o[4];
#pragma unroll
  for (int nt2 = 0; nt2 < 4; nt2++) o[nt2] = (fx4){0.f, 0.f, 0.f, 0.f};
  float m_i[4] = {-1e30f, -1e30f, -1e30f, -1e30f};
  float l_i[4] = {0.f, 0.f, 0.f, 0.f};

  int n = (qt + 2) >> 1;     // 64-key tiles this q-block needs
  int R = (n + 1) >> 1;      // rounds per kt-group

  if (g < n) stage_kv(kbb, vtb, stg[g][0][0], stg[g][0][1], g, rw, lane);

  for (int rr = 0; rr < R; rr++) {
    __syncthreads();                       // publishes buf rr&1 (drains vmcnt)
    int tn = 2 * (rr + 1) + g;
    if (tn < n)
      stage_kv(kbb, vtb, stg[g][(rr + 1) & 1][0], stg[g][(rr + 1) & 1][1], tn, rw, lane);
    int t = 2 * rr + g;
    if (t < n) {
      const u16* Kb = stg[g][rr & 1][0];
      const u16* Vb = stg[g][rr & 1][1];
      fx4 sA[4];
#pragma unroll
      for (int nt = 0; nt < 4; nt++) {
        int row = nt * 16 + ln;
        int s0_ = quad ^ (row & 7), s1_ = (quad + 4) ^ (row & 7);
        short8 kf0 = *(const short8*)(Kb + row * 64 + s0_ * 8);
        short8 kf1 = *(const short8*)(Kb + row * 64 + s1_ * 8);
        sA[nt] = mfma16(qf0, kf0, (fx4){0.f, 0.f, 0.f, 0.f});
        sA[nt] = mfma16(qf1, kf1, sA[nt]);
      }
      if (t == n - 1) {  // only the diagonal-overlapping tile needs masking
#pragma unroll
        for (int nt = 0; nt < 4; nt++)
#pragma unroll
          for (int reg = 0; reg < 4; reg++) {
            int col = t * 64 + nt * 16 + ln;
            int rowg = q0 + rw * 16 + quad * 4 + reg;
            if (col > rowg) sA[nt][reg] = -1e30f;
          }
      }
      float alpha[4];
#pragma unroll
      for (int reg = 0; reg < 4; reg++) {
        float v = fmaxf(fmaxf(sA[0][reg], sA[1][reg]), fmaxf(sA[2][reg], sA[3][reg]));
#pragma unroll
        for (int off = 1; off < 16; off <<= 1) v = fmaxf(v, __shfl_xor(v, off));
        float mn = fmaxf(m_i[reg], v);
        alpha[reg] = __expf(m_i[reg] - mn);
        m_i[reg] = mn;
      }
      float p[4][4];
#pragma unroll
      for (int nt = 0; nt < 4; nt++)
#pragma unroll
        for (int reg = 0; reg < 4; reg++) p[nt][reg] = __expf(sA[nt][reg] - m_i[reg]);
#pragma unroll
      for (int reg = 0; reg < 4; reg++) {
        float sgm = p[0][reg] + p[1][reg] + p[2][reg] + p[3][reg];
#pragma unroll
        for (int off = 1; off < 16; off <<= 1) sgm += __shfl_xor(sgm, off);
        l_i[reg] = l_i[reg] * alpha[reg] + sgm;
      }
#pragma unroll
      for (int nt2 = 0; nt2 < 4; nt2++)
#pragma unroll
        for (int reg = 0; reg < 4; reg++) o[nt2][reg] *= alpha[reg];

#pragma unroll
      for (int nt = 0; nt < 4; nt++)
#pragma unroll
        for (int reg = 0; reg < 4; reg++)
          Ps[w][(quad * 4 + reg) * 72 + nt * 16 + ln] = f2bf(p[nt][reg]);

      short8 pf0 = *(const short8*)(&Ps[w][ln * 72 + quad * 8]);
      short8 pf1 = *(const short8*)(&Ps[w][ln * 72 + 32 + quad * 8]);
#pragma unroll
      for (int nt2 = 0; nt2 < 4; nt2++) {
        int row = nt2 * 16 + ln;
        int s0_ = quad ^ (row & 7), s1_ = (quad + 4) ^ (row & 7);
        short8 vf0 = *(const short8*)(Vb + row * 64 + s0_ * 8);
        short8 vf1 = *(const short8*)(Vb + row * 64 + s1_ * 8);
        o[nt2] = mfma16(pf0, vf0, o[nt2]);
        o[nt2] = mfma16(pf1, vf1, o[nt2]);
      }
    }
  }

  // merge the two kt-groups' partial (m,l,o) per Q-row, then normalize + store
  __syncthreads();
  float* cmb = (float*)&stg[0][0][0][0];   // o: [rw][16][68]; m at 2176, l at 2208
  if (g == 1) {
#pragma unroll
    for (int nt2 = 0; nt2 < 4; nt2++)
#pragma unroll
      for (int reg = 0; reg < 4; reg++)
        cmb[rw * 1088 + (quad * 4 + reg) * 68 + nt2 * 16 + ln] = o[nt2][reg];
    if (ln == 0) {
#pragma unroll
      for (int reg = 0; reg < 4; reg++) {
        cmb[2176 + rw * 16 + quad * 4 + reg] = m_i[reg];
        cmb[2208 + rw * 16 + quad * 4 + reg] = l_i[reg];
      }
    }
  }
  __syncthreads();
  if (g == 0) {
    float a0[4], a1[4], inv[4];
#pragma unroll
    for (int reg = 0; reg < 4; reg++) {
      float m1 = cmb[2176 + rw * 16 + quad * 4 + reg];
      float l1 = cmb[2208 + rw * 16 + quad * 4 + reg];
      float mf = fmaxf(m_i[reg], m1);
      a0[reg] = __expf(m_i[reg] - mf);
      a1[reg] = __expf(m1 - mf);
      inv[reg] = 1.0f / (l_i[reg] * a0[reg] + l1 * a1[reg]);
    }
#pragma unroll
    for (int nt2 = 0; nt2 < 4; nt2++)
#pragma unroll
      for (int reg = 0; reg < 4; reg++) {
        float o1 = cmb[rw * 1088 + (quad * 4 + reg) * 68 + nt2 * 16 + ln];
        int rowg = q0 + rw * 16 + quad * 4 + reg;
        outb[(size_t)rowg * 64 + nt2 * 16 + ln] =
            (o[nt2][reg] * a0[reg] + o1 * a1[reg]) * inv[reg];
      }
  }
}

extern "C" void kernel_launch(void* const* d_in, const int* in_sizes, int n_in,
                              void* d_out, int out_size, void* d_ws, size_t ws_size,
                              hipStream_t stream) {
  const float* x  = (const float*)d_in[0];
  const float* Wq = (const float*)d_in[1];
  const float* Wk = (const float*)d_in[2];
  const float* Wv = (const float*)d_in[3];

  u16* qbw = (u16*)d_ws;                          // [16384][64] bf16
  u16* kbw = qbw + (size_t)TOKENS * 64;           // [16384][64] bf16
  u16* vtw = kbw + (size_t)TOKENS * 64;           // [4][64][4096] bf16
  u16* wfr = vtw + (size_t)TOKENS * 64;           // [3][24][4][64][8] bf16

  prep_w_kernel<<<72, 256, 0, stream>>>(Wq, Wk, Wv, wfr);
  proj_kernel<<<TOKENS / 32, 256, 0, stream>>>(x, wfr, qbw, kbw, vtw);
  attn_kernel<<<dim3(128, 4), 256, 0, stream>>>(qbw, kbw, vtw, (float*)d_out);
}